// Round 15
// baseline (103.994 us; speedup 1.0000x reference)
//
#include <hip/hip_runtime.h>
#include <hip/hip_bf16.h>

typedef __attribute__((ext_vector_type(4))) float f32x4;
typedef __attribute__((ext_vector_type(8))) short s16x8;

#define DEVI __device__ __forceinline__

constexpr int S = 512, C = 862, P = 96, H = 128, BATCH = 64;

DEVI short f2bf(float f) {
  unsigned u = __builtin_bit_cast(unsigned, f);
  u += 0x7fffu + ((u >> 16) & 1u);
  return (short)(u >> 16);
}

DEVI unsigned pk2(float a, float b) {
  return (unsigned)(unsigned short)f2bf(a) | ((unsigned)(unsigned short)f2bf(b) << 16);
}

DEVI s16x8 mk8(const float* v) {
  s16x8 r;
#pragma unroll
  for (int i = 0; i < 8; ++i) r[i] = f2bf(v[i]);
  return r;
}

// async global->LDS 16B per lane; lds dest = wave-uniform base (+lane*16 implied)
DEVI void gload16(const void* g, void* l) {
  __builtin_amdgcn_global_load_lds(
      (const __attribute__((address_space(1))) void*)g,
      (__attribute__((address_space(3))) void*)l, 16, 0, 0);
}

// Redistribute lane-local D-tiles (packed bf16 pairs p01/p23, tiles 0..2*NK-1)
// into MFMA B-fragments f[kc], kc = 0..NK-1 (k = kc*32 + l4*8 + i). (r4/r5 verified)
template <int NK>
DEVI void redistN(const unsigned* p01, const unsigned* p23, int sA, int hi,
                  s16x8* f) {
#pragma unroll
  for (int kc = 0; kc < NK; ++kc) {
    unsigned a0 = __shfl(p01[2 * kc], sA),      b0 = __shfl(p01[2 * kc + 1], sA);
    unsigned a1 = __shfl(p23[2 * kc], sA),      b1 = __shfl(p23[2 * kc + 1], sA);
    unsigned a2 = __shfl(p01[2 * kc], sA + 16), b2 = __shfl(p01[2 * kc + 1], sA + 16);
    unsigned a3 = __shfl(p23[2 * kc], sA + 16), b3 = __shfl(p23[2 * kc + 1], sA + 16);
    union { s16x8 v; unsigned u[4]; } t;
    t.u[0] = hi ? b0 : a0;
    t.u[1] = hi ? b1 : a1;
    t.u[2] = hi ? b2 : a2;
    t.u[3] = hi ? b3 : a3;
    f[kc] = t.v;
  }
}

// ---------------- k0: weight conversions (round-5 proven layouts) ----------------
__global__ __launch_bounds__(256) void k0_convert(
    const float* __restrict__ W1, const float* __restrict__ Wp,
    const float* __restrict__ W2, const float* __restrict__ mem,
    short* __restrict__ W1b, short* __restrict__ WpS, short* __restrict__ W2b,
    short* __restrict__ membS, short* __restrict__ memTS) {
  int i = blockIdx.x * 256 + threadIdx.x;
  if (i < 65536) { W1b[i] = f2bf(W1[i]); return; }  // plain [h][s]
  i -= 65536;
  if (i < 16384) {  // Wp [g][h] -> swizzled rows of 128
    int g = i >> 7, h = i & 127;
    WpS[(g << 7) + (h ^ ((g & 7) << 3))] = f2bf(Wp[i]);
    return;
  }
  i -= 16384;
  if (i < 24576) { W2b[i] = f2bf(W2[i]); return; }  // plain [p][256]
  i -= 24576;
  if (i < 65536) {
    int f = i >> 7, d = i & 127;
    short v = f2bf(mem[i]);
    membS[((f >> 6) << 13) + ((f & 63) << 7) + (d ^ ((f & 7) << 3))] = v;
    memTS[((f >> 6) << 13) + (d << 6) + ((f & 63) ^ ((d & 7) << 3))] = v;
  }
}

// ---------------- k12: FUSED repre + projector + codebook attention + predictor ----------------
// grid (7, 64), 512 thr = 8 waves x 16 c-rows. LDS 49.7KB -> 3 blocks/CU (24 waves).
// Phase 1: single-buffered xt/w1t, 2 barriers/kt. Phase 2: memb dbuf + memT single
// (staged under logits/softmax of same slice), Wp transient. Defer-max kept.
__global__ __launch_bounds__(512, 6) void k12_fused(
    const float* __restrict__ x, const short* __restrict__ W1b,
    const float* __restrict__ b1, const short* __restrict__ WpS,
    const float* __restrict__ bp, const short* __restrict__ membS,
    const short* __restrict__ memTS, const short* __restrict__ W2b,
    const float* __restrict__ b2, float* __restrict__ out) {
  __shared__ __align__(16) char lds[49664];  // == resf 128*97*4; peak of all phases
  float* resf = (float*)lds;

  const int b = blockIdx.y, c0 = blockIdx.x * 128;
  const int valid = (C - c0 < 128) ? (C - c0) : 128;
  const int tid = threadIdx.x, l = tid & 63, w = tid >> 6;  // w: 0..7
  const int l15 = l & 15, l4 = l >> 4;
  const int sA = l15 + 32 * (l4 & 1);
  const int hi = (l4 >> 1) & 1;
  const int xr = (l15 & 7) << 4;   // row-XOR for phase-2 swizzled frag reads
  const int cb = l4 * 16;          // k-column byte base
  const int rloc = 16 * w + l15;   // this lane's c-row, 0..127

  // ================= PHASE 1: r1 = sigmoid(x^T W1^T + b1) =================
  // xt [128c][64s] @0 (16KB, single), w1t [128h][64s] @16K (16KB, single)
  s16x8 rb[4];
  {
    short* xt = (short*)lds;
    short* w1t = (short*)(lds + 16384);
    const int cme = tid & 127, o2 = tid >> 7;  // o2: 0..3
    const bool cv = (c0 + cme) < C;
    const float* xsrc0 = x + (size_t)b * S * C + c0 + cme;
    const int hh = tid >> 2, qq = tid & 3;

    f32x4 acc[8];
#pragma unroll
    for (int t = 0; t < 8; ++t) acc[t] = (f32x4){0.f, 0.f, 0.f, 0.f};

    float xv[2][8];
    s16x8 wv[2];
    // prologue: kt=0
    {
#pragma unroll
      for (int j = 0; j < 2; ++j) {
        const float* src = xsrc0 + (size_t)((o2 + j * 4) * 8) * C;
#pragma unroll
        for (int i = 0; i < 8; ++i) xv[j][i] = cv ? src[(size_t)i * C] : 0.f;
      }
      const short* wsrc = W1b + hh * 512;
      wv[0] = *(const s16x8*)&wsrc[qq * 8];
      wv[1] = *(const s16x8*)&wsrc[(qq + 4) * 8];
    }

    for (int kt = 0; kt < 8; ++kt) {
      // write staged regs -> single LDS buffers (prev reads done at barB(kt-1))
#pragma unroll
      for (int j = 0; j < 2; ++j)
        *(s16x8*)&xt[cme * 64 + ((o2 + j * 4) ^ (cme & 7)) * 8] = mk8(xv[j]);
      *(s16x8*)&w1t[hh * 64 + (qq ^ (hh & 7)) * 8] = wv[0];
      *(s16x8*)&w1t[hh * 64 + ((qq + 4) ^ (hh & 7)) * 8] = wv[1];
      __syncthreads();  // barA: writes visible
      // 1-deep prefetch of tile kt+1
      if (kt < 7) {
        int kn = kt + 1;
#pragma unroll
        for (int j = 0; j < 2; ++j) {
          const float* src = xsrc0 + (size_t)(kn * 64 + (o2 + j * 4) * 8) * C;
#pragma unroll
          for (int i = 0; i < 8; ++i) xv[j][i] = cv ? src[(size_t)i * C] : 0.f;
        }
        const short* wsrc = W1b + hh * 512 + kn * 64;
        wv[0] = *(const s16x8*)&wsrc[qq * 8];
        wv[1] = *(const s16x8*)&wsrc[(qq + 4) * 8];
      }
      // fragments + MFMA
      s16x8 bx[2];
#pragma unroll
      for (int kc = 0; kc < 2; ++kc)
        bx[kc] = *(const s16x8*)&xt[rloc * 64 + ((kc * 4 + l4) ^ (l15 & 7)) * 8];
#pragma unroll
      for (int t = 0; t < 8; ++t) {
#pragma unroll
        for (int kc = 0; kc < 2; ++kc) {
          s16x8 af = *(const s16x8*)&w1t[(t * 16 + l15) * 64 + ((kc * 4 + l4) ^ (l15 & 7)) * 8];
          acc[t] = __builtin_amdgcn_mfma_f32_16x16x32_bf16(af, bx[kc], acc[t], 0, 0, 0);
        }
      }
      __syncthreads();  // barB: all reads done; buffers free for next kt / phase 2
    }

    // issue phase-2 prologue staging NOW (overlaps epilogue VALU):
    // Wp -> [16K,48K), memb(0) -> [0,16K)
    {
      const char* gwp = (const char*)WpS;
      const char* gmb = (const char*)membS;
#pragma unroll
      for (int i = 0; i < 4; ++i) {
        int o = (w * 4 + i) * 1024;
        gload16(gwp + o + l * 16, lds + 16384 + o);
      }
#pragma unroll
      for (int i = 0; i < 2; ++i) {
        int o = (w * 2 + i) * 1024;
        gload16(gmb + o + l * 16, lds + o);
      }
    }

    // bias + sigmoid + pack -> rb (r1 row rloc as B-fragments)
    unsigned p01[8], p23[8];
#pragma unroll
    for (int t = 0; t < 8; ++t) {
      f32x4 bq = *(const f32x4*)&b1[t * 16 + l4 * 4];
      float s0 = 1.f / (1.f + __expf(-(acc[t][0] + bq[0])));
      float s1 = 1.f / (1.f + __expf(-(acc[t][1] + bq[1])));
      float s2 = 1.f / (1.f + __expf(-(acc[t][2] + bq[2])));
      float s3 = 1.f / (1.f + __expf(-(acc[t][3] + bq[3])));
      p01[t] = pk2(s0, s1);
      p23[t] = pk2(s2, s3);
    }
    redistN<4>(p01, p23, sA, hi, rb);
  }
  __syncthreads();  // Wp + memb(0) staged

  // ---- r2 = r1 @ Wp^T + bp (A = Wp rows from LDS @16K) ----
  unsigned rpk01[8], rpk23[8];
  {
    const char* bufWp = lds + 16384;
#pragma unroll
    for (int gt = 0; gt < 8; ++gt) {
      f32x4 acc = (f32x4){0.f, 0.f, 0.f, 0.f};
#pragma unroll
      for (int kc = 0; kc < 4; ++kc) {
        s16x8 af = *(const s16x8*)(bufWp + (gt * 16 + l15) * 256 + ((kc * 64 + cb) ^ xr));
        acc = __builtin_amdgcn_mfma_f32_16x16x32_bf16(af, rb[kc], acc, 0, 0, 0);
      }
      f32x4 bq = *(const f32x4*)&bp[gt * 16 + l4 * 4];
      rpk01[gt] = pk2(acc[0] + bq[0], acc[1] + bq[1]);
      rpk23[gt] = pk2(acc[2] + bq[2], acc[3] + bq[3]);
    }
  }
  s16x8 r2f[4];
  redistN<4>(rpk01, rpk23, sA, hi, r2f);

  float m_run = -1e30f, s_run = 0.f;
  f32x4 oacc[8];
#pragma unroll
  for (int dt = 0; dt < 8; ++dt) oacc[dt] = (f32x4){0.f, 0.f, 0.f, 0.f};

  // ---- slice loop: memb dbuf @0/16K, memT single @32K ----
  for (int s5 = 0; s5 < 8; ++s5) {
    __syncthreads();  // barA: PV(s5-1) reads done (s5=0: Wp reads done); stages drained
    // issue memT(s5) -> [32K,48K)  (s5=0 overwrites Wp upper half; reads done)
    {
      const char* gmt = (const char*)memTS + (size_t)s5 * 16384;
#pragma unroll
      for (int i = 0; i < 2; ++i) {
        int o = (w * 2 + i) * 1024;
        gload16(gmt + o + l * 16, lds + 32768 + o);
      }
    }
    // issue memb(s5+1) -> slot((s5+1)&1)  (holds memb(s5-1); reads done)
    if (s5 < 7) {
      const char* gmb = (const char*)membS + (size_t)(s5 + 1) * 16384;
#pragma unroll
      for (int i = 0; i < 2; ++i) {
        int o = (w * 2 + i) * 1024;
        gload16(gmb + o + l * 16, lds + (((s5 + 1) & 1) << 14) + o);
      }
    }
    // logits(s5) from memb slot(s5&1)
    f32x4 lg[4];
    {
      const char* bmb = lds + ((s5 & 1) << 14);
#pragma unroll
      for (int ft = 0; ft < 4; ++ft) {
        lg[ft] = (f32x4){0.f, 0.f, 0.f, 0.f};
#pragma unroll
        for (int kc = 0; kc < 4; ++kc) {
          s16x8 af = *(const s16x8*)(bmb + (ft * 16 + l15) * 256 + ((kc * 64 + cb) ^ xr));
          lg[ft] = __builtin_amdgcn_mfma_f32_16x16x32_bf16(af, r2f[kc], lg[ft], 0, 0, 0);
        }
      }
    }
    // online softmax with defer-max (T13, THR=8)
    s16x8 pf[2];
    {
      float mx = lg[0][0];
#pragma unroll
      for (int ft = 0; ft < 4; ++ft)
#pragma unroll
        for (int e = 0; e < 4; ++e) mx = fmaxf(mx, lg[ft][e]);
      mx = fmaxf(mx, __shfl_xor(mx, 16));
      mx = fmaxf(mx, __shfl_xor(mx, 32));
      if (s5 == 0) {
        m_run = mx;
      } else if (!__all(mx <= m_run + 8.f)) {
        float mn = fmaxf(m_run, mx);
        float sc = __expf(m_run - mn);
        s_run *= sc;
        m_run = mn;
#pragma unroll
        for (int dt = 0; dt < 8; ++dt)
#pragma unroll
          for (int e = 0; e < 4; ++e) oacc[dt][e] *= sc;
      }
      float ps = 0.f;
      unsigned ppk01[4], ppk23[4];
#pragma unroll
      for (int ft = 0; ft < 4; ++ft) {
#pragma unroll
        for (int e = 0; e < 4; ++e) {
          float p = __expf(lg[ft][e] - m_run);
          lg[ft][e] = p;
          ps += p;
        }
        ppk01[ft] = pk2(lg[ft][0], lg[ft][1]);
        ppk23[ft] = pk2(lg[ft][2], lg[ft][3]);
      }
      ps += __shfl_xor(ps, 16);
      ps += __shfl_xor(ps, 32);
      s_run += ps;
      redistN<2>(ppk01, ppk23, sA, hi, pf);
    }
    __syncthreads();  // barB: memT(s5) (+ memb(s5+1)) drained
    // PV(s5): A = memT d-rows @32K
    {
      const char* bmt = lds + 32768;
#pragma unroll
      for (int dt = 0; dt < 8; ++dt) {
#pragma unroll
        for (int kc = 0; kc < 2; ++kc) {
          s16x8 af = *(const s16x8*)(bmt + (dt * 16 + l15) * 128 + ((kc * 64 + cb) ^ xr));
          oacc[dt] = __builtin_amdgcn_mfma_f32_16x16x32_bf16(af, pf[kc], oacc[dt], 0, 0, 0);
        }
      }
    }
  }
  __syncthreads();  // all slice LDS reads done before resf overwrite

  // normalize att-out, pack, redistribute
  s16x8 of[4];
  {
    float inv = 1.f / s_run;
    unsigned opk01[8], opk23[8];
#pragma unroll
    for (int dt = 0; dt < 8; ++dt) {
      opk01[dt] = pk2(oacc[dt][0] * inv, oacc[dt][1] * inv);
      opk23[dt] = pk2(oacc[dt][2] * inv, oacc[dt][3] * inv);
    }
    redistN<4>(opk01, opk23, sA, hi, of);
  }

  // final GEMM: A = W2 p-rows (global, L2-resident), B = [att|r2]
#pragma unroll
  for (int pt = 0; pt < 6; ++pt) {
    f32x4 acc = (f32x4){0.f, 0.f, 0.f, 0.f};
#pragma unroll
    for (int kc = 0; kc < 4; ++kc) {
      s16x8 af = *(const s16x8*)&W2b[(pt * 16 + l15) * 256 + kc * 32 + l4 * 8];
      acc = __builtin_amdgcn_mfma_f32_16x16x32_bf16(af, of[kc], acc, 0, 0, 0);
    }
#pragma unroll
    for (int kc = 0; kc < 4; ++kc) {
      s16x8 af = *(const s16x8*)&W2b[(pt * 16 + l15) * 256 + 128 + kc * 32 + l4 * 8];
      acc = __builtin_amdgcn_mfma_f32_16x16x32_bf16(af, r2f[kc], acc, 0, 0, 0);
    }
    f32x4 bq = *(const f32x4*)&b2[pt * 16 + l4 * 4];
#pragma unroll
    for (int e = 0; e < 4; ++e)
      resf[rloc * 97 + pt * 16 + l4 * 4 + e] = acc[e] + bq[e];
  }
  __syncthreads();
  // coalesced transposed store (256B segments)
  {
    int c = tid & 127, p0 = tid >> 7;
    if (c < valid) {
      float* dst = out + (size_t)b * P * C + c0 + c;
#pragma unroll
      for (int j = 0; j < 24; ++j) {
        int p = p0 + j * 4;
        dst[(size_t)p * C] = resf[c * 97 + p];
      }
    }
  }
}

extern "C" void kernel_launch(void* const* d_in, const int* in_sizes, int n_in,
                              void* d_out, int out_size, void* d_ws, size_t ws_size,
                              hipStream_t stream) {
  const float* x   = (const float*)d_in[0];
  const float* W1  = (const float*)d_in[1];
  const float* b1  = (const float*)d_in[2];
  const float* Wp  = (const float*)d_in[3];
  const float* bpv = (const float*)d_in[4];
  const float* W2  = (const float*)d_in[5];
  const float* b2  = (const float*)d_in[6];
  const float* mem = (const float*)d_in[7];
  char* ws = (char*)d_ws;
  short* W1b   = (short*)(ws);             // 131072 B (plain [h][s])
  short* WpS   = (short*)(ws + 131072);    // 32768 B  (swizzled)
  short* W2b   = (short*)(ws + 163840);    // 49152 B  (plain)
  short* membS = (short*)(ws + 212992);    // 131072 B (slice-major, swizzled)
  short* memTS = (short*)(ws + 344064);    // 131072 B (slice-major, swizzled)
  float* outp = (float*)d_out;

  k0_convert<<<672, 256, 0, stream>>>(W1, Wp, W2, mem, W1b, WpS, W2b, membS, memTS);
  dim3 grid(7, BATCH);
  k12_fused<<<grid, 512, 0, stream>>>(x, W1b, b1, WpS, bpv, membS, memTS, W2b, b2, outp);
}

// Round 16
// 83.325 us; speedup vs baseline: 1.2481x; 1.2481x over previous
//
#include <hip/hip_runtime.h>
#include <hip/hip_bf16.h>

typedef __attribute__((ext_vector_type(4))) float f32x4;
typedef __attribute__((ext_vector_type(8))) short s16x8;

#define DEVI __device__ __forceinline__

constexpr int S = 512, C = 862, P = 96, H = 128, BATCH = 64;

DEVI short f2bf(float f) {
  unsigned u = __builtin_bit_cast(unsigned, f);
  u += 0x7fffu + ((u >> 16) & 1u);
  return (short)(u >> 16);
}

DEVI unsigned pk2(float a, float b) {
  return (unsigned)(unsigned short)f2bf(a) | ((unsigned)(unsigned short)f2bf(b) << 16);
}

DEVI s16x8 mk8(const float* v) {
  s16x8 r;
#pragma unroll
  for (int i = 0; i < 8; ++i) r[i] = f2bf(v[i]);
  return r;
}

// async global->LDS 16B per lane; lds dest = wave-uniform base (+lane*16 implied)
DEVI void gload16(const void* g, void* l) {
  __builtin_amdgcn_global_load_lds(
      (const __attribute__((address_space(1))) void*)g,
      (__attribute__((address_space(3))) void*)l, 16, 0, 0);
}

// Redistribute lane-local D-tiles (packed bf16 pairs p01/p23, tiles 0..2*NK-1)
// into MFMA B-fragments f[kc], kc = 0..NK-1 (k = kc*32 + l4*8 + i). (r4/r5 verified)
template <int NK>
DEVI void redistN(const unsigned* p01, const unsigned* p23, int sA, int hi,
                  s16x8* f) {
#pragma unroll
  for (int kc = 0; kc < NK; ++kc) {
    unsigned a0 = __shfl(p01[2 * kc], sA),      b0 = __shfl(p01[2 * kc + 1], sA);
    unsigned a1 = __shfl(p23[2 * kc], sA),      b1 = __shfl(p23[2 * kc + 1], sA);
    unsigned a2 = __shfl(p01[2 * kc], sA + 16), b2 = __shfl(p01[2 * kc + 1], sA + 16);
    unsigned a3 = __shfl(p23[2 * kc], sA + 16), b3 = __shfl(p23[2 * kc + 1], sA + 16);
    union { s16x8 v; unsigned u[4]; } t;
    t.u[0] = hi ? b0 : a0;
    t.u[1] = hi ? b1 : a1;
    t.u[2] = hi ? b2 : a2;
    t.u[3] = hi ? b3 : a3;
    f[kc] = t.v;
  }
}

// ---------------- k0: weight conversions (round-5 proven layouts) ----------------
__global__ __launch_bounds__(256) void k0_convert(
    const float* __restrict__ W1, const float* __restrict__ Wp,
    const float* __restrict__ W2, const float* __restrict__ mem,
    short* __restrict__ W1b, short* __restrict__ WpS, short* __restrict__ W2b,
    short* __restrict__ membS, short* __restrict__ memTS) {
  int i = blockIdx.x * 256 + threadIdx.x;
  if (i < 65536) { W1b[i] = f2bf(W1[i]); return; }  // plain [h][s]
  i -= 65536;
  if (i < 16384) {  // Wp [g][h] -> swizzled rows of 128
    int g = i >> 7, h = i & 127;
    WpS[(g << 7) + (h ^ ((g & 7) << 3))] = f2bf(Wp[i]);
    return;
  }
  i -= 16384;
  if (i < 24576) { W2b[i] = f2bf(W2[i]); return; }  // plain [p][256]
  i -= 24576;
  if (i < 65536) {
    int f = i >> 7, d = i & 127;
    short v = f2bf(mem[i]);
    membS[((f >> 6) << 13) + ((f & 63) << 7) + (d ^ ((f & 7) << 3))] = v;
    memTS[((f >> 6) << 13) + (d << 6) + ((f & 63) ^ ((d & 7) << 3))] = v;
  }
}

// ---------------- k12: FUSED repre + projector + codebook attention + predictor ----------------
// grid (7, 64), 512 thr = 8 waves x 16 c-rows. LDS 49.7KB -> 3 blocks/CU (24 waves).
// launch_bounds (512,3): VGPR cap 85 (hipcc's arg2 acts as blocks/CU for 8-wave
// blocks: (512,4)->cap 64 [r12], (512,6)->cap 40+spill [r15]). Natural use ~64-75.
// Phase 1: single-buffered xt/w1t, 2 barriers/kt. Phase 2: memb dbuf + memT single.
__global__ __launch_bounds__(512, 3) void k12_fused(
    const float* __restrict__ x, const short* __restrict__ W1b,
    const float* __restrict__ b1, const short* __restrict__ WpS,
    const float* __restrict__ bp, const short* __restrict__ membS,
    const short* __restrict__ memTS, const short* __restrict__ W2b,
    const float* __restrict__ b2, float* __restrict__ out) {
  __shared__ __align__(16) char lds[49664];  // == resf 128*97*4; peak of all phases
  float* resf = (float*)lds;

  const int b = blockIdx.y, c0 = blockIdx.x * 128;
  const int valid = (C - c0 < 128) ? (C - c0) : 128;
  const int tid = threadIdx.x, l = tid & 63, w = tid >> 6;  // w: 0..7
  const int l15 = l & 15, l4 = l >> 4;
  const int sA = l15 + 32 * (l4 & 1);
  const int hi = (l4 >> 1) & 1;
  const int xr = (l15 & 7) << 4;   // row-XOR for phase-2 swizzled frag reads
  const int cb = l4 * 16;          // k-column byte base
  const int rloc = 16 * w + l15;   // this lane's c-row, 0..127

  // ================= PHASE 1: r1 = sigmoid(x^T W1^T + b1) =================
  // xt [128c][64s] @0 (16KB, single), w1t [128h][64s] @16K (16KB, single)
  s16x8 rb[4];
  {
    short* xt = (short*)lds;
    short* w1t = (short*)(lds + 16384);
    const int cme = tid & 127, o2 = tid >> 7;  // o2: 0..3
    const bool cv = (c0 + cme) < C;
    const float* xsrc0 = x + (size_t)b * S * C + c0 + cme;
    const int hh = tid >> 2, qq = tid & 3;

    f32x4 acc[8];
#pragma unroll
    for (int t = 0; t < 8; ++t) acc[t] = (f32x4){0.f, 0.f, 0.f, 0.f};

    float xv[2][8];
    s16x8 wv[2];
    // prologue: kt=0
    {
#pragma unroll
      for (int j = 0; j < 2; ++j) {
        const float* src = xsrc0 + (size_t)((o2 + j * 4) * 8) * C;
#pragma unroll
        for (int i = 0; i < 8; ++i) xv[j][i] = cv ? src[(size_t)i * C] : 0.f;
      }
      const short* wsrc = W1b + hh * 512;
      wv[0] = *(const s16x8*)&wsrc[qq * 8];
      wv[1] = *(const s16x8*)&wsrc[(qq + 4) * 8];
    }

    for (int kt = 0; kt < 8; ++kt) {
      // write staged regs -> single LDS buffers (prev reads done at barB(kt-1))
#pragma unroll
      for (int j = 0; j < 2; ++j)
        *(s16x8*)&xt[cme * 64 + ((o2 + j * 4) ^ (cme & 7)) * 8] = mk8(xv[j]);
      *(s16x8*)&w1t[hh * 64 + (qq ^ (hh & 7)) * 8] = wv[0];
      *(s16x8*)&w1t[hh * 64 + ((qq + 4) ^ (hh & 7)) * 8] = wv[1];
      __syncthreads();  // barA: writes visible
      // 1-deep prefetch of tile kt+1
      if (kt < 7) {
        int kn = kt + 1;
#pragma unroll
        for (int j = 0; j < 2; ++j) {
          const float* src = xsrc0 + (size_t)(kn * 64 + (o2 + j * 4) * 8) * C;
#pragma unroll
          for (int i = 0; i < 8; ++i) xv[j][i] = cv ? src[(size_t)i * C] : 0.f;
        }
        const short* wsrc = W1b + hh * 512 + kn * 64;
        wv[0] = *(const s16x8*)&wsrc[qq * 8];
        wv[1] = *(const s16x8*)&wsrc[(qq + 4) * 8];
      }
      // fragments + MFMA
      s16x8 bx[2];
#pragma unroll
      for (int kc = 0; kc < 2; ++kc)
        bx[kc] = *(const s16x8*)&xt[rloc * 64 + ((kc * 4 + l4) ^ (l15 & 7)) * 8];
#pragma unroll
      for (int t = 0; t < 8; ++t) {
#pragma unroll
        for (int kc = 0; kc < 2; ++kc) {
          s16x8 af = *(const s16x8*)&w1t[(t * 16 + l15) * 64 + ((kc * 4 + l4) ^ (l15 & 7)) * 8];
          acc[t] = __builtin_amdgcn_mfma_f32_16x16x32_bf16(af, bx[kc], acc[t], 0, 0, 0);
        }
      }
      __syncthreads();  // barB: all reads done; buffers free for next kt / phase 2
    }

    // issue phase-2 prologue staging NOW (overlaps epilogue VALU):
    // Wp -> [16K,48K), memb(0) -> [0,16K)
    {
      const char* gwp = (const char*)WpS;
      const char* gmb = (const char*)membS;
#pragma unroll
      for (int i = 0; i < 4; ++i) {
        int o = (w * 4 + i) * 1024;
        gload16(gwp + o + l * 16, lds + 16384 + o);
      }
#pragma unroll
      for (int i = 0; i < 2; ++i) {
        int o = (w * 2 + i) * 1024;
        gload16(gmb + o + l * 16, lds + o);
      }
    }

    // bias + sigmoid + pack -> rb (r1 row rloc as B-fragments)
    unsigned p01[8], p23[8];
#pragma unroll
    for (int t = 0; t < 8; ++t) {
      f32x4 bq = *(const f32x4*)&b1[t * 16 + l4 * 4];
      float s0 = 1.f / (1.f + __expf(-(acc[t][0] + bq[0])));
      float s1 = 1.f / (1.f + __expf(-(acc[t][1] + bq[1])));
      float s2 = 1.f / (1.f + __expf(-(acc[t][2] + bq[2])));
      float s3 = 1.f / (1.f + __expf(-(acc[t][3] + bq[3])));
      p01[t] = pk2(s0, s1);
      p23[t] = pk2(s2, s3);
    }
    redistN<4>(p01, p23, sA, hi, rb);
  }
  __syncthreads();  // Wp + memb(0) staged

  // ---- r2 = r1 @ Wp^T + bp (A = Wp rows from LDS @16K) ----
  unsigned rpk01[8], rpk23[8];
  {
    const char* bufWp = lds + 16384;
#pragma unroll
    for (int gt = 0; gt < 8; ++gt) {
      f32x4 acc = (f32x4){0.f, 0.f, 0.f, 0.f};
#pragma unroll
      for (int kc = 0; kc < 4; ++kc) {
        s16x8 af = *(const s16x8*)(bufWp + (gt * 16 + l15) * 256 + ((kc * 64 + cb) ^ xr));
        acc = __builtin_amdgcn_mfma_f32_16x16x32_bf16(af, rb[kc], acc, 0, 0, 0);
      }
      f32x4 bq = *(const f32x4*)&bp[gt * 16 + l4 * 4];
      rpk01[gt] = pk2(acc[0] + bq[0], acc[1] + bq[1]);
      rpk23[gt] = pk2(acc[2] + bq[2], acc[3] + bq[3]);
    }
  }
  s16x8 r2f[4];
  redistN<4>(rpk01, rpk23, sA, hi, r2f);

  float m_run = -1e30f, s_run = 0.f;
  f32x4 oacc[8];
#pragma unroll
  for (int dt = 0; dt < 8; ++dt) oacc[dt] = (f32x4){0.f, 0.f, 0.f, 0.f};

  // ---- slice loop: memb dbuf @0/16K, memT single @32K ----
  for (int s5 = 0; s5 < 8; ++s5) {
    __syncthreads();  // barA: PV(s5-1) reads done (s5=0: Wp reads done); stages drained
    // issue memT(s5) -> [32K,48K)  (s5=0 overwrites Wp upper half; reads done)
    {
      const char* gmt = (const char*)memTS + (size_t)s5 * 16384;
#pragma unroll
      for (int i = 0; i < 2; ++i) {
        int o = (w * 2 + i) * 1024;
        gload16(gmt + o + l * 16, lds + 32768 + o);
      }
    }
    // issue memb(s5+1) -> slot((s5+1)&1)  (holds memb(s5-1); reads done)
    if (s5 < 7) {
      const char* gmb = (const char*)membS + (size_t)(s5 + 1) * 16384;
#pragma unroll
      for (int i = 0; i < 2; ++i) {
        int o = (w * 2 + i) * 1024;
        gload16(gmb + o + l * 16, lds + (((s5 + 1) & 1) << 14) + o);
      }
    }
    // logits(s5) from memb slot(s5&1)
    f32x4 lg[4];
    {
      const char* bmb = lds + ((s5 & 1) << 14);
#pragma unroll
      for (int ft = 0; ft < 4; ++ft) {
        lg[ft] = (f32x4){0.f, 0.f, 0.f, 0.f};
#pragma unroll
        for (int kc = 0; kc < 4; ++kc) {
          s16x8 af = *(const s16x8*)(bmb + (ft * 16 + l15) * 256 + ((kc * 64 + cb) ^ xr));
          lg[ft] = __builtin_amdgcn_mfma_f32_16x16x32_bf16(af, r2f[kc], lg[ft], 0, 0, 0);
        }
      }
    }
    // online softmax with defer-max (T13, THR=8)
    s16x8 pf[2];
    {
      float mx = lg[0][0];
#pragma unroll
      for (int ft = 0; ft < 4; ++ft)
#pragma unroll
        for (int e = 0; e < 4; ++e) mx = fmaxf(mx, lg[ft][e]);
      mx = fmaxf(mx, __shfl_xor(mx, 16));
      mx = fmaxf(mx, __shfl_xor(mx, 32));
      if (s5 == 0) {
        m_run = mx;
      } else if (!__all(mx <= m_run + 8.f)) {
        float mn = fmaxf(m_run, mx);
        float sc = __expf(m_run - mn);
        s_run *= sc;
        m_run = mn;
#pragma unroll
        for (int dt = 0; dt < 8; ++dt)
#pragma unroll
          for (int e = 0; e < 4; ++e) oacc[dt][e] *= sc;
      }
      float ps = 0.f;
      unsigned ppk01[4], ppk23[4];
#pragma unroll
      for (int ft = 0; ft < 4; ++ft) {
#pragma unroll
        for (int e = 0; e < 4; ++e) {
          float p = __expf(lg[ft][e] - m_run);
          lg[ft][e] = p;
          ps += p;
        }
        ppk01[ft] = pk2(lg[ft][0], lg[ft][1]);
        ppk23[ft] = pk2(lg[ft][2], lg[ft][3]);
      }
      ps += __shfl_xor(ps, 16);
      ps += __shfl_xor(ps, 32);
      s_run += ps;
      redistN<2>(ppk01, ppk23, sA, hi, pf);
    }
    __syncthreads();  // barB: memT(s5) (+ memb(s5+1)) drained
    // PV(s5): A = memT d-rows @32K
    {
      const char* bmt = lds + 32768;
#pragma unroll
      for (int dt = 0; dt < 8; ++dt) {
#pragma unroll
        for (int kc = 0; kc < 2; ++kc) {
          s16x8 af = *(const s16x8*)(bmt + (dt * 16 + l15) * 128 + ((kc * 64 + cb) ^ xr));
          oacc[dt] = __builtin_amdgcn_mfma_f32_16x16x32_bf16(af, pf[kc], oacc[dt], 0, 0, 0);
        }
      }
    }
  }
  __syncthreads();  // all slice LDS reads done before resf overwrite

  // normalize att-out, pack, redistribute
  s16x8 of[4];
  {
    float inv = 1.f / s_run;
    unsigned opk01[8], opk23[8];
#pragma unroll
    for (int dt = 0; dt < 8; ++dt) {
      opk01[dt] = pk2(oacc[dt][0] * inv, oacc[dt][1] * inv);
      opk23[dt] = pk2(oacc[dt][2] * inv, oacc[dt][3] * inv);
    }
    redistN<4>(opk01, opk23, sA, hi, of);
  }

  // final GEMM: A = W2 p-rows (global, L2-resident), B = [att|r2]
#pragma unroll
  for (int pt = 0; pt < 6; ++pt) {
    f32x4 acc = (f32x4){0.f, 0.f, 0.f, 0.f};
#pragma unroll
    for (int kc = 0; kc < 4; ++kc) {
      s16x8 af = *(const s16x8*)&W2b[(pt * 16 + l15) * 256 + kc * 32 + l4 * 8];
      acc = __builtin_amdgcn_mfma_f32_16x16x32_bf16(af, of[kc], acc, 0, 0, 0);
    }
#pragma unroll
    for (int kc = 0; kc < 4; ++kc) {
      s16x8 af = *(const s16x8*)&W2b[(pt * 16 + l15) * 256 + 128 + kc * 32 + l4 * 8];
      acc = __builtin_amdgcn_mfma_f32_16x16x32_bf16(af, r2f[kc], acc, 0, 0, 0);
    }
    f32x4 bq = *(const f32x4*)&b2[pt * 16 + l4 * 4];
#pragma unroll
    for (int e = 0; e < 4; ++e)
      resf[rloc * 97 + pt * 16 + l4 * 4 + e] = acc[e] + bq[e];
  }
  __syncthreads();
  // coalesced transposed store (256B segments)
  {
    int c = tid & 127, p0 = tid >> 7;
    if (c < valid) {
      float* dst = out + (size_t)b * P * C + c0 + c;
#pragma unroll
      for (int j = 0; j < 24; ++j) {
        int p = p0 + j * 4;
        dst[(size_t)p * C] = resf[c * 97 + p];
      }
    }
  }
}

extern "C" void kernel_launch(void* const* d_in, const int* in_sizes, int n_in,
                              void* d_out, int out_size, void* d_ws, size_t ws_size,
                              hipStream_t stream) {
  const float* x   = (const float*)d_in[0];
  const float* W1  = (const float*)d_in[1];
  const float* b1  = (const float*)d_in[2];
  const float* Wp  = (const float*)d_in[3];
  const float* bpv = (const float*)d_in[4];
  const float* W2  = (const float*)d_in[5];
  const float* b2  = (const float*)d_in[6];
  const float* mem = (const float*)d_in[7];
  char* ws = (char*)d_ws;
  short* W1b   = (short*)(ws);             // 131072 B (plain [h][s])
  short* WpS   = (short*)(ws + 131072);    // 32768 B  (swizzled)
  short* W2b   = (short*)(ws + 163840);    // 49152 B  (plain)
  short* membS = (short*)(ws + 212992);    // 131072 B (slice-major, swizzled)
  short* memTS = (short*)(ws + 344064);    // 131072 B (slice-major, swizzled)
  float* outp = (float*)d_out;

  k0_convert<<<672, 256, 0, stream>>>(W1, Wp, W2, mem, W1b, WpS, W2b, membS, memTS);
  dim3 grid(7, BATCH);
  k12_fused<<<grid, 512, 0, stream>>>(x, W1b, b1, WpS, bpv, membS, memTS, W2b, b2, outp);
}

// Round 17
// 82.286 us; speedup vs baseline: 1.2638x; 1.0126x over previous
//
#include <hip/hip_runtime.h>
#include <hip/hip_bf16.h>

typedef __attribute__((ext_vector_type(4))) float f32x4;
typedef __attribute__((ext_vector_type(8))) short s16x8;

#define DEVI __device__ __forceinline__

constexpr int S = 512, C = 862, P = 96, H = 128, BATCH = 64;

DEVI short f2bf(float f) {
  unsigned u = __builtin_bit_cast(unsigned, f);
  u += 0x7fffu + ((u >> 16) & 1u);
  return (short)(u >> 16);
}

DEVI unsigned pk2(float a, float b) {
  return (unsigned)(unsigned short)f2bf(a) | ((unsigned)(unsigned short)f2bf(b) << 16);
}

DEVI s16x8 mk8(const float* v) {
  s16x8 r;
#pragma unroll
  for (int i = 0; i < 8; ++i) r[i] = f2bf(v[i]);
  return r;
}

// async global->LDS 16B per lane; lds dest = wave-uniform base (+lane*16 implied)
DEVI void gload16(const void* g, void* l) {
  __builtin_amdgcn_global_load_lds(
      (const __attribute__((address_space(1))) void*)g,
      (__attribute__((address_space(3))) void*)l, 16, 0, 0);
}

// Redistribute lane-local D-tiles (packed bf16 pairs p01/p23, tiles 0..2*NK-1)
// into MFMA B-fragments f[kc], kc = 0..NK-1 (k = kc*32 + l4*8 + i). (r4/r5 verified)
template <int NK>
DEVI void redistN(const unsigned* p01, const unsigned* p23, int sA, int hi,
                  s16x8* f) {
#pragma unroll
  for (int kc = 0; kc < NK; ++kc) {
    unsigned a0 = __shfl(p01[2 * kc], sA),      b0 = __shfl(p01[2 * kc + 1], sA);
    unsigned a1 = __shfl(p23[2 * kc], sA),      b1 = __shfl(p23[2 * kc + 1], sA);
    unsigned a2 = __shfl(p01[2 * kc], sA + 16), b2 = __shfl(p01[2 * kc + 1], sA + 16);
    unsigned a3 = __shfl(p23[2 * kc], sA + 16), b3 = __shfl(p23[2 * kc + 1], sA + 16);
    union { s16x8 v; unsigned u[4]; } t;
    t.u[0] = hi ? b0 : a0;
    t.u[1] = hi ? b1 : a1;
    t.u[2] = hi ? b2 : a2;
    t.u[3] = hi ? b3 : a3;
    f[kc] = t.v;
  }
}

// ---------------- k0: weight conversions (round-5 proven layouts) ----------------
__global__ __launch_bounds__(256) void k0_convert(
    const float* __restrict__ W1, const float* __restrict__ Wp,
    const float* __restrict__ W2, const float* __restrict__ mem,
    short* __restrict__ W1b, short* __restrict__ WpS, short* __restrict__ W2b,
    short* __restrict__ membS, short* __restrict__ memTS) {
  int i = blockIdx.x * 256 + threadIdx.x;
  if (i < 65536) { W1b[i] = f2bf(W1[i]); return; }  // plain [h][s]
  i -= 65536;
  if (i < 16384) {  // Wp [g][h] -> swizzled rows of 128
    int g = i >> 7, h = i & 127;
    WpS[(g << 7) + (h ^ ((g & 7) << 3))] = f2bf(Wp[i]);
    return;
  }
  i -= 16384;
  if (i < 24576) { W2b[i] = f2bf(W2[i]); return; }  // plain [p][256]
  i -= 24576;
  if (i < 65536) {
    int f = i >> 7, d = i & 127;
    short v = f2bf(mem[i]);
    membS[((f >> 6) << 13) + ((f & 63) << 7) + (d ^ ((f & 7) << 3))] = v;
    memTS[((f >> 6) << 13) + (d << 6) + ((f & 63) ^ ((d & 7) << 3))] = v;
  }
}

// ---------------- k12: FUSED repre + projector + codebook attention + predictor ----------------
// grid (7, 64), 512 thr = 8 waves x 16 c-rows. LDS 49.7KB.
// Grid is 448 blocks -> 3584 waves total = work-limited occupancy (max 43.75%);
// launch_bounds (512,2) (cap 128) tells the scheduler the TRUE occupancy target so it
// can keep all 16 prefetch x-loads in flight (at cap 85 it chose 60 VGPR and
// serialized them). Prefetch issued BEFORE barA: barrier sync time covers latency.
__global__ __launch_bounds__(512, 2) void k12_fused(
    const float* __restrict__ x, const short* __restrict__ W1b,
    const float* __restrict__ b1, const short* __restrict__ WpS,
    const float* __restrict__ bp, const short* __restrict__ membS,
    const short* __restrict__ memTS, const short* __restrict__ W2b,
    const float* __restrict__ b2, float* __restrict__ out) {
  __shared__ __align__(16) char lds[49664];  // == resf 128*97*4; peak of all phases
  float* resf = (float*)lds;

  const int b = blockIdx.y, c0 = blockIdx.x * 128;
  const int valid = (C - c0 < 128) ? (C - c0) : 128;
  const int tid = threadIdx.x, l = tid & 63, w = tid >> 6;  // w: 0..7
  const int l15 = l & 15, l4 = l >> 4;
  const int sA = l15 + 32 * (l4 & 1);
  const int hi = (l4 >> 1) & 1;
  const int xr = (l15 & 7) << 4;   // row-XOR for phase-2 swizzled frag reads
  const int cb = l4 * 16;          // k-column byte base
  const int rloc = 16 * w + l15;   // this lane's c-row, 0..127

  // ================= PHASE 1: r1 = sigmoid(x^T W1^T + b1) =================
  // xt [128c][64s] @0 (16KB, single), w1t [128h][64s] @16K (16KB, single)
  s16x8 rb[4];
  {
    short* xt = (short*)lds;
    short* w1t = (short*)(lds + 16384);
    const int cme = tid & 127, o2 = tid >> 7;  // o2: 0..3
    const bool cv = (c0 + cme) < C;
    const float* xsrc0 = x + (size_t)b * S * C + c0 + cme;
    const int hh = tid >> 2, qq = tid & 3;

    f32x4 acc[8];
#pragma unroll
    for (int t = 0; t < 8; ++t) acc[t] = (f32x4){0.f, 0.f, 0.f, 0.f};

    float xv[2][8];
    s16x8 wv[2];
    // prologue: kt=0
    {
#pragma unroll
      for (int j = 0; j < 2; ++j) {
        const float* src = xsrc0 + (size_t)((o2 + j * 4) * 8) * C;
#pragma unroll
        for (int i = 0; i < 8; ++i) xv[j][i] = cv ? src[(size_t)i * C] : 0.f;
      }
      const short* wsrc = W1b + hh * 512;
      wv[0] = *(const s16x8*)&wsrc[qq * 8];
      wv[1] = *(const s16x8*)&wsrc[(qq + 4) * 8];
    }

    for (int kt = 0; kt < 8; ++kt) {
      // write staged regs -> single LDS buffers (prev reads done at barB(kt-1))
#pragma unroll
      for (int j = 0; j < 2; ++j)
        *(s16x8*)&xt[cme * 64 + ((o2 + j * 4) ^ (cme & 7)) * 8] = mk8(xv[j]);
      *(s16x8*)&w1t[hh * 64 + (qq ^ (hh & 7)) * 8] = wv[0];
      *(s16x8*)&w1t[hh * 64 + ((qq + 4) ^ (hh & 7)) * 8] = wv[1];
      // issue prefetch of tile kt+1 BEFORE the barrier (regs are dead after
      // the ds_writes above; barrier sync adds to the load-latency cover)
      if (kt < 7) {
        int kn = kt + 1;
#pragma unroll
        for (int j = 0; j < 2; ++j) {
          const float* src = xsrc0 + (size_t)(kn * 64 + (o2 + j * 4) * 8) * C;
#pragma unroll
          for (int i = 0; i < 8; ++i) xv[j][i] = cv ? src[(size_t)i * C] : 0.f;
        }
        const short* wsrc = W1b + hh * 512 + kn * 64;
        wv[0] = *(const s16x8*)&wsrc[qq * 8];
        wv[1] = *(const s16x8*)&wsrc[(qq + 4) * 8];
      }
      __syncthreads();  // barA: ds_writes visible
      // fragments + MFMA
      s16x8 bx[2];
#pragma unroll
      for (int kc = 0; kc < 2; ++kc)
        bx[kc] = *(const s16x8*)&xt[rloc * 64 + ((kc * 4 + l4) ^ (l15 & 7)) * 8];
#pragma unroll
      for (int t = 0; t < 8; ++t) {
#pragma unroll
        for (int kc = 0; kc < 2; ++kc) {
          s16x8 af = *(const s16x8*)&w1t[(t * 16 + l15) * 64 + ((kc * 4 + l4) ^ (l15 & 7)) * 8];
          acc[t] = __builtin_amdgcn_mfma_f32_16x16x32_bf16(af, bx[kc], acc[t], 0, 0, 0);
        }
      }
      __syncthreads();  // barB: all reads done; buffers free for next kt / phase 2
    }

    // issue phase-2 prologue staging NOW (overlaps epilogue VALU):
    // Wp -> [16K,48K), memb(0) -> [0,16K)
    {
      const char* gwp = (const char*)WpS;
      const char* gmb = (const char*)membS;
#pragma unroll
      for (int i = 0; i < 4; ++i) {
        int o = (w * 4 + i) * 1024;
        gload16(gwp + o + l * 16, lds + 16384 + o);
      }
#pragma unroll
      for (int i = 0; i < 2; ++i) {
        int o = (w * 2 + i) * 1024;
        gload16(gmb + o + l * 16, lds + o);
      }
    }

    // bias + sigmoid + pack -> rb (r1 row rloc as B-fragments)
    unsigned p01[8], p23[8];
#pragma unroll
    for (int t = 0; t < 8; ++t) {
      f32x4 bq = *(const f32x4*)&b1[t * 16 + l4 * 4];
      float s0 = 1.f / (1.f + __expf(-(acc[t][0] + bq[0])));
      float s1 = 1.f / (1.f + __expf(-(acc[t][1] + bq[1])));
      float s2 = 1.f / (1.f + __expf(-(acc[t][2] + bq[2])));
      float s3 = 1.f / (1.f + __expf(-(acc[t][3] + bq[3])));
      p01[t] = pk2(s0, s1);
      p23[t] = pk2(s2, s3);
    }
    redistN<4>(p01, p23, sA, hi, rb);
  }
  __syncthreads();  // Wp + memb(0) staged

  // ---- r2 = r1 @ Wp^T + bp (A = Wp rows from LDS @16K) ----
  unsigned rpk01[8], rpk23[8];
  {
    const char* bufWp = lds + 16384;
#pragma unroll
    for (int gt = 0; gt < 8; ++gt) {
      f32x4 acc = (f32x4){0.f, 0.f, 0.f, 0.f};
#pragma unroll
      for (int kc = 0; kc < 4; ++kc) {
        s16x8 af = *(const s16x8*)(bufWp + (gt * 16 + l15) * 256 + ((kc * 64 + cb) ^ xr));
        acc = __builtin_amdgcn_mfma_f32_16x16x32_bf16(af, rb[kc], acc, 0, 0, 0);
      }
      f32x4 bq = *(const f32x4*)&bp[gt * 16 + l4 * 4];
      rpk01[gt] = pk2(acc[0] + bq[0], acc[1] + bq[1]);
      rpk23[gt] = pk2(acc[2] + bq[2], acc[3] + bq[3]);
    }
  }
  s16x8 r2f[4];
  redistN<4>(rpk01, rpk23, sA, hi, r2f);

  float m_run = -1e30f, s_run = 0.f;
  f32x4 oacc[8];
#pragma unroll
  for (int dt = 0; dt < 8; ++dt) oacc[dt] = (f32x4){0.f, 0.f, 0.f, 0.f};

  // ---- slice loop: memb dbuf @0/16K, memT single @32K ----
  for (int s5 = 0; s5 < 8; ++s5) {
    __syncthreads();  // barA: PV(s5-1) reads done (s5=0: Wp reads done); stages drained
    // issue memT(s5) -> [32K,48K)  (s5=0 overwrites Wp upper half; reads done)
    {
      const char* gmt = (const char*)memTS + (size_t)s5 * 16384;
#pragma unroll
      for (int i = 0; i < 2; ++i) {
        int o = (w * 2 + i) * 1024;
        gload16(gmt + o + l * 16, lds + 32768 + o);
      }
    }
    // issue memb(s5+1) -> slot((s5+1)&1)  (holds memb(s5-1); reads done)
    if (s5 < 7) {
      const char* gmb = (const char*)membS + (size_t)(s5 + 1) * 16384;
#pragma unroll
      for (int i = 0; i < 2; ++i) {
        int o = (w * 2 + i) * 1024;
        gload16(gmb + o + l * 16, lds + (((s5 + 1) & 1) << 14) + o);
      }
    }
    // logits(s5) from memb slot(s5&1)
    f32x4 lg[4];
    {
      const char* bmb = lds + ((s5 & 1) << 14);
#pragma unroll
      for (int ft = 0; ft < 4; ++ft) {
        lg[ft] = (f32x4){0.f, 0.f, 0.f, 0.f};
#pragma unroll
        for (int kc = 0; kc < 4; ++kc) {
          s16x8 af = *(const s16x8*)(bmb + (ft * 16 + l15) * 256 + ((kc * 64 + cb) ^ xr));
          lg[ft] = __builtin_amdgcn_mfma_f32_16x16x32_bf16(af, r2f[kc], lg[ft], 0, 0, 0);
        }
      }
    }
    // online softmax with defer-max (T13, THR=8)
    s16x8 pf[2];
    {
      float mx = lg[0][0];
#pragma unroll
      for (int ft = 0; ft < 4; ++ft)
#pragma unroll
        for (int e = 0; e < 4; ++e) mx = fmaxf(mx, lg[ft][e]);
      mx = fmaxf(mx, __shfl_xor(mx, 16));
      mx = fmaxf(mx, __shfl_xor(mx, 32));
      if (s5 == 0) {
        m_run = mx;
      } else if (!__all(mx <= m_run + 8.f)) {
        float mn = fmaxf(m_run, mx);
        float sc = __expf(m_run - mn);
        s_run *= sc;
        m_run = mn;
#pragma unroll
        for (int dt = 0; dt < 8; ++dt)
#pragma unroll
          for (int e = 0; e < 4; ++e) oacc[dt][e] *= sc;
      }
      float ps = 0.f;
      unsigned ppk01[4], ppk23[4];
#pragma unroll
      for (int ft = 0; ft < 4; ++ft) {
#pragma unroll
        for (int e = 0; e < 4; ++e) {
          float p = __expf(lg[ft][e] - m_run);
          lg[ft][e] = p;
          ps += p;
        }
        ppk01[ft] = pk2(lg[ft][0], lg[ft][1]);
        ppk23[ft] = pk2(lg[ft][2], lg[ft][3]);
      }
      ps += __shfl_xor(ps, 16);
      ps += __shfl_xor(ps, 32);
      s_run += ps;
      redistN<2>(ppk01, ppk23, sA, hi, pf);
    }
    __syncthreads();  // barB: memT(s5) (+ memb(s5+1)) drained
    // PV(s5): A = memT d-rows @32K
    {
      const char* bmt = lds + 32768;
#pragma unroll
      for (int dt = 0; dt < 8; ++dt) {
#pragma unroll
        for (int kc = 0; kc < 2; ++kc) {
          s16x8 af = *(const s16x8*)(bmt + (dt * 16 + l15) * 128 + ((kc * 64 + cb) ^ xr));
          oacc[dt] = __builtin_amdgcn_mfma_f32_16x16x32_bf16(af, pf[kc], oacc[dt], 0, 0, 0);
        }
      }
    }
  }
  __syncthreads();  // all slice LDS reads done before resf overwrite

  // normalize att-out, pack, redistribute
  s16x8 of[4];
  {
    float inv = 1.f / s_run;
    unsigned opk01[8], opk23[8];
#pragma unroll
    for (int dt = 0; dt < 8; ++dt) {
      opk01[dt] = pk2(oacc[dt][0] * inv, oacc[dt][1] * inv);
      opk23[dt] = pk2(oacc[dt][2] * inv, oacc[dt][3] * inv);
    }
    redistN<4>(opk01, opk23, sA, hi, of);
  }

  // final GEMM: A = W2 p-rows (global, L2-resident), B = [att|r2]
#pragma unroll
  for (int pt = 0; pt < 6; ++pt) {
    f32x4 acc = (f32x4){0.f, 0.f, 0.f, 0.f};
#pragma unroll
    for (int kc = 0; kc < 4; ++kc) {
      s16x8 af = *(const s16x8*)&W2b[(pt * 16 + l15) * 256 + kc * 32 + l4 * 8];
      acc = __builtin_amdgcn_mfma_f32_16x16x32_bf16(af, of[kc], acc, 0, 0, 0);
    }
#pragma unroll
    for (int kc = 0; kc < 4; ++kc) {
      s16x8 af = *(const s16x8*)&W2b[(pt * 16 + l15) * 256 + 128 + kc * 32 + l4 * 8];
      acc = __builtin_amdgcn_mfma_f32_16x16x32_bf16(af, r2f[kc], acc, 0, 0, 0);
    }
    f32x4 bq = *(const f32x4*)&b2[pt * 16 + l4 * 4];
#pragma unroll
    for (int e = 0; e < 4; ++e)
      resf[rloc * 97 + pt * 16 + l4 * 4 + e] = acc[e] + bq[e];
  }
  __syncthreads();
  // coalesced transposed store (256B segments)
  {
    int c = tid & 127, p0 = tid >> 7;
    if (c < valid) {
      float* dst = out + (size_t)b * P * C + c0 + c;
#pragma unroll
      for (int j = 0; j < 24; ++j) {
        int p = p0 + j * 4;
        dst[(size_t)p * C] = resf[c * 97 + p];
      }
    }
  }
}

extern "C" void kernel_launch(void* const* d_in, const int* in_sizes, int n_in,
                              void* d_out, int out_size, void* d_ws, size_t ws_size,
                              hipStream_t stream) {
  const float* x   = (const float*)d_in[0];
  const float* W1  = (const float*)d_in[1];
  const float* b1  = (const float*)d_in[2];
  const float* Wp  = (const float*)d_in[3];
  const float* bpv = (const float*)d_in[4];
  const float* W2  = (const float*)d_in[5];
  const float* b2  = (const float*)d_in[6];
  const float* mem = (const float*)d_in[7];
  char* ws = (char*)d_ws;
  short* W1b   = (short*)(ws);             // 131072 B (plain [h][s])
  short* WpS   = (short*)(ws + 131072);    // 32768 B  (swizzled)
  short* W2b   = (short*)(ws + 163840);    // 49152 B  (plain)
  short* membS = (short*)(ws + 212992);    // 131072 B (slice-major, swizzled)
  short* memTS = (short*)(ws + 344064);    // 131072 B (slice-major, swizzled)
  float* outp = (float*)d_out;

  k0_convert<<<672, 256, 0, stream>>>(W1, Wp, W2, mem, W1b, WpS, W2b, membS, memTS);
  dim3 grid(7, BATCH);
  k12_fused<<<grid, 512, 0, stream>>>(x, W1b, b1, WpS, bpv, membS, memTS, W2b, b2, outp);
}